// Round 1
// baseline (1237.898 us; speedup 1.0000x reference)
//
#include <hip/hip_runtime.h>

#define NNODES 50000
#define NEDGES 640000
#define DIM 128

// K1: h_pre = x   (into d_out, which doubles as scratch; fully overwritten later)
__global__ void copy_k(const float4* __restrict__ src, float4* __restrict__ dst, int n4) {
    int i = blockIdx.x * blockDim.x + threadIdx.x;
    if (i < n4) dst[i] = src[i];
}

// K2: h_pre[dst] += x[src]  -- 32 lanes per edge, one float4 per lane
__global__ void scatter_k(const float4* __restrict__ x4, const int* __restrict__ ei,
                          float* __restrict__ hp, int E) {
    int t = blockIdx.x * blockDim.x + threadIdx.x;
    int e = t >> 5;
    if (e >= E) return;
    int lane = t & 31;
    int src = ei[e];
    int dst = ei[E + e];
    float4 v = x4[(size_t)src * 32 + lane];
    float* p = hp + (size_t)dst * DIM + lane * 4;
    unsafeAtomicAdd(p + 0, v.x);
    unsafeAtomicAdd(p + 1, v.y);
    unsafeAtomicAdd(p + 2, v.z);
    unsafeAtomicAdd(p + 3, v.w);
}

// K3: fused MLP, in-place on io. Block = 256 threads handles 32 rows.
// LDS: W (64KB) + transposed A tile (16KB) = 80KB -> 2 blocks/CU.
// Thread (tc=tid&31, tr=tid>>5) computes rows tr*4..tr*4+3 x cols tc*4..tc*4+3.
__launch_bounds__(256)
__global__ void mlp_k(float* __restrict__ io,
                      const float* __restrict__ W1, const float* __restrict__ b1,
                      const float* __restrict__ W2, const float* __restrict__ b2,
                      int N) {
    __shared__ float Wl[DIM * DIM];   // 64 KB
    __shared__ float At[DIM][32];     // 16 KB, At[k][r]

    const int tid = threadIdx.x;
    const int r0 = blockIdx.x * 32;
    const int tc = tid & 31;
    const int tr = tid >> 5;   // 0..7

    // stage W1 into LDS (coalesced float4)
    {
        const float4* w4 = (const float4*)W1;
        float4* wl4 = (float4*)Wl;
        #pragma unroll
        for (int i = 0; i < 16; ++i) wl4[tid + i * 256] = w4[tid + i * 256];
    }
    // stage A tile transposed: global read coalesced (lane -> k4), scalar LDS writes
    {
        const float4* io4 = (const float4*)io;
        #pragma unroll
        for (int i = 0; i < 4; ++i) {
            int p = tid + i * 256;     // 0..1023
            int row = p >> 5;          // 0..31
            int k4 = p & 31;           // 0..31 consecutive per lane -> coalesced
            float4 v = make_float4(0.f, 0.f, 0.f, 0.f);
            if (r0 + row < N) v = io4[(size_t)(r0 + row) * 32 + k4];
            At[k4 * 4 + 0][row] = v.x;
            At[k4 * 4 + 1][row] = v.y;
            At[k4 * 4 + 2][row] = v.z;
            At[k4 * 4 + 3][row] = v.w;
        }
    }
    __syncthreads();

    // ---- layer 1 ----
    float acc[4][4];
    #pragma unroll
    for (int i = 0; i < 4; ++i)
        #pragma unroll
        for (int j = 0; j < 4; ++j) acc[i][j] = 0.f;

    #pragma unroll 4
    for (int k = 0; k < DIM; ++k) {
        float4 a = *(const float4*)&At[k][tr * 4];
        float4 w = *(const float4*)&Wl[k * DIM + tc * 4];
        float av[4] = {a.x, a.y, a.z, a.w};
        float wv[4] = {w.x, w.y, w.z, w.w};
        #pragma unroll
        for (int i = 0; i < 4; ++i)
            #pragma unroll
            for (int j = 0; j < 4; ++j)
                acc[i][j] = fmaf(av[i], wv[j], acc[i][j]);
    }

    float4 bv1 = ((const float4*)b1)[tc];
    float h[4][4];
    #pragma unroll
    for (int i = 0; i < 4; ++i) {
        h[i][0] = fmaxf(acc[i][0] + bv1.x, 0.f);
        h[i][1] = fmaxf(acc[i][1] + bv1.y, 0.f);
        h[i][2] = fmaxf(acc[i][2] + bv1.z, 0.f);
        h[i][3] = fmaxf(acc[i][3] + bv1.w, 0.f);
    }

    __syncthreads();  // everyone done reading W1/At

    // stage W2; write h transposed back into At (layer-2's k dim = layer-1's col dim)
    {
        const float4* w4 = (const float4*)W2;
        float4* wl4 = (float4*)Wl;
        #pragma unroll
        for (int i = 0; i < 16; ++i) wl4[tid + i * 256] = w4[tid + i * 256];
    }
    #pragma unroll
    for (int ci = 0; ci < 4; ++ci)
        #pragma unroll
        for (int ri = 0; ri < 4; ++ri)
            At[tc * 4 + ci][tr * 4 + ri] = h[ri][ci];
    __syncthreads();

    // ---- layer 2 ----
    #pragma unroll
    for (int i = 0; i < 4; ++i)
        #pragma unroll
        for (int j = 0; j < 4; ++j) acc[i][j] = 0.f;

    #pragma unroll 4
    for (int k = 0; k < DIM; ++k) {
        float4 a = *(const float4*)&At[k][tr * 4];
        float4 w = *(const float4*)&Wl[k * DIM + tc * 4];
        float av[4] = {a.x, a.y, a.z, a.w};
        float wv[4] = {w.x, w.y, w.z, w.w};
        #pragma unroll
        for (int i = 0; i < 4; ++i)
            #pragma unroll
            for (int j = 0; j < 4; ++j)
                acc[i][j] = fmaf(av[i], wv[j], acc[i][j]);
    }

    float4 bv2 = ((const float4*)b2)[tc];
    float4* io4 = (float4*)io;
    #pragma unroll
    for (int ri = 0; ri < 4; ++ri) {
        int row = r0 + tr * 4 + ri;
        if (row < N) {
            float4 o = make_float4(acc[ri][0] + bv2.x, acc[ri][1] + bv2.y,
                                   acc[ri][2] + bv2.z, acc[ri][3] + bv2.w);
            io4[(size_t)row * 32 + tc] = o;
        }
    }
}

extern "C" void kernel_launch(void* const* d_in, const int* in_sizes, int n_in,
                              void* d_out, int out_size, void* d_ws, size_t ws_size,
                              hipStream_t stream) {
    const float* x  = (const float*)d_in[0];
    const int*   ei = (const int*)d_in[1];
    const float* W1 = (const float*)d_in[2];
    const float* b1 = (const float*)d_in[3];
    const float* W2 = (const float*)d_in[4];
    const float* b2 = (const float*)d_in[5];
    float* out = (float*)d_out;

    int n4 = NNODES * DIM / 4;
    copy_k<<<(n4 + 255) / 256, 256, 0, stream>>>((const float4*)x, (float4*)out, n4);

    int sthreads = NEDGES * 32;
    scatter_k<<<(sthreads + 255) / 256, 256, 0, stream>>>((const float4*)x, ei, out, NEDGES);

    mlp_k<<<(NNODES + 31) / 32, 256, 0, stream>>>(out, W1, b1, W2, b2, NNODES);
}

// Round 2
// 381.646 us; speedup vs baseline: 3.2436x; 3.2436x over previous
//
#include <hip/hip_runtime.h>

#define NNODES 50000
#define NEDGES 640000
#define DIM 128

// ---------------- CSR build ----------------

__global__ void zero_k(int* __restrict__ p, int n) {
    int i = blockIdx.x * blockDim.x + threadIdx.x;
    if (i < n) p[i] = 0;
}

// deg[dst]++ for each edge
__global__ void hist_k(const int* __restrict__ ei, int* __restrict__ deg, int E) {
    int e = blockIdx.x * blockDim.x + threadIdx.x;
    if (e < E) atomicAdd(&deg[ei[E + e]], 1);
}

// exclusive scan of degcur[0..N) -> off[0..N]; degcur reset to running base (cursor)
__global__ void scan_k(int* __restrict__ degcur, int* __restrict__ off, int E) {
    __shared__ int s[256];
    const int t = threadIdx.x;
    const int CH = (NNODES + 255) / 256;  // 196
    const int lo = t * CH;
    const int hi = min(lo + CH, NNODES);
    int sum = 0;
    for (int i = lo; i < hi; ++i) sum += degcur[i];
    s[t] = sum;
    __syncthreads();
    for (int d = 1; d < 256; d <<= 1) {
        int v = (t >= d) ? s[t - d] : 0;
        __syncthreads();
        s[t] += v;
        __syncthreads();
    }
    int run = s[t] - sum;  // exclusive base for this chunk
    for (int i = lo; i < hi; ++i) {
        int dv = degcur[i];
        off[i] = run;
        degcur[i] = run;   // becomes the fill cursor
        run += dv;
    }
    if (t == 255) off[NNODES] = E;
}

// srclist[cur[dst]++] = src
__global__ void fill_k(const int* __restrict__ ei, int* __restrict__ cur,
                       int* __restrict__ srclist, int E) {
    int e = blockIdx.x * blockDim.x + threadIdx.x;
    if (e >= E) return;
    int src = ei[e];
    int dst = ei[E + e];
    int pos = atomicAdd(&cur[dst], 1);
    srclist[pos] = src;
}

// ---------------- gather aggregation (no atomics) ----------------
// 32 lanes per node, one float4 per lane. h_pre = x[node] + sum_j x[srclist[j]]
__global__ void gather_k(const float4* __restrict__ x4, const int* __restrict__ off,
                         const int* __restrict__ srclist, float4* __restrict__ hp4) {
    int t = blockIdx.x * blockDim.x + threadIdx.x;
    int node = t >> 5;
    if (node >= NNODES) return;
    int lane = t & 31;
    float4 acc = x4[(size_t)node * 32 + lane];
    int beg = off[node], end = off[node + 1];
    for (int j = beg; j < end; ++j) {
        int s = srclist[j];
        float4 v = x4[(size_t)s * 32 + lane];
        acc.x += v.x; acc.y += v.y; acc.z += v.z; acc.w += v.w;
    }
    hp4[(size_t)node * 32 + lane] = acc;
}

// ---------------- fallback atomic scatter (if ws too small) ----------------
__global__ void copy_k(const float4* __restrict__ src, float4* __restrict__ dst, int n4) {
    int i = blockIdx.x * blockDim.x + threadIdx.x;
    if (i < n4) dst[i] = src[i];
}

__global__ void scatter_k(const float4* __restrict__ x4, const int* __restrict__ ei,
                          float* __restrict__ hp, int E) {
    int t = blockIdx.x * blockDim.x + threadIdx.x;
    int e = t >> 5;
    if (e >= E) return;
    int lane = t & 31;
    int src = ei[e];
    int dst = ei[E + e];
    float4 v = x4[(size_t)src * 32 + lane];
    float* p = hp + (size_t)dst * DIM + lane * 4;
    unsafeAtomicAdd(p + 0, v.x);
    unsafeAtomicAdd(p + 1, v.y);
    unsafeAtomicAdd(p + 2, v.z);
    unsafeAtomicAdd(p + 3, v.w);
}

// ---------------- fused MLP (unchanged from R1) ----------------
__launch_bounds__(256)
__global__ void mlp_k(float* __restrict__ io,
                      const float* __restrict__ W1, const float* __restrict__ b1,
                      const float* __restrict__ W2, const float* __restrict__ b2,
                      int N) {
    __shared__ float Wl[DIM * DIM];   // 64 KB
    __shared__ float At[DIM][32];     // 16 KB

    const int tid = threadIdx.x;
    const int r0 = blockIdx.x * 32;
    const int tc = tid & 31;
    const int tr = tid >> 5;

    {
        const float4* w4 = (const float4*)W1;
        float4* wl4 = (float4*)Wl;
        #pragma unroll
        for (int i = 0; i < 16; ++i) wl4[tid + i * 256] = w4[tid + i * 256];
    }
    {
        const float4* io4 = (const float4*)io;
        #pragma unroll
        for (int i = 0; i < 4; ++i) {
            int p = tid + i * 256;
            int row = p >> 5;
            int k4 = p & 31;
            float4 v = make_float4(0.f, 0.f, 0.f, 0.f);
            if (r0 + row < N) v = io4[(size_t)(r0 + row) * 32 + k4];
            At[k4 * 4 + 0][row] = v.x;
            At[k4 * 4 + 1][row] = v.y;
            At[k4 * 4 + 2][row] = v.z;
            At[k4 * 4 + 3][row] = v.w;
        }
    }
    __syncthreads();

    float acc[4][4];
    #pragma unroll
    for (int i = 0; i < 4; ++i)
        #pragma unroll
        for (int j = 0; j < 4; ++j) acc[i][j] = 0.f;

    #pragma unroll 4
    for (int k = 0; k < DIM; ++k) {
        float4 a = *(const float4*)&At[k][tr * 4];
        float4 w = *(const float4*)&Wl[k * DIM + tc * 4];
        float av[4] = {a.x, a.y, a.z, a.w};
        float wv[4] = {w.x, w.y, w.z, w.w};
        #pragma unroll
        for (int i = 0; i < 4; ++i)
            #pragma unroll
            for (int j = 0; j < 4; ++j)
                acc[i][j] = fmaf(av[i], wv[j], acc[i][j]);
    }

    float4 bv1 = ((const float4*)b1)[tc];
    float h[4][4];
    #pragma unroll
    for (int i = 0; i < 4; ++i) {
        h[i][0] = fmaxf(acc[i][0] + bv1.x, 0.f);
        h[i][1] = fmaxf(acc[i][1] + bv1.y, 0.f);
        h[i][2] = fmaxf(acc[i][2] + bv1.z, 0.f);
        h[i][3] = fmaxf(acc[i][3] + bv1.w, 0.f);
    }

    __syncthreads();

    {
        const float4* w4 = (const float4*)W2;
        float4* wl4 = (float4*)Wl;
        #pragma unroll
        for (int i = 0; i < 16; ++i) wl4[tid + i * 256] = w4[tid + i * 256];
    }
    #pragma unroll
    for (int ci = 0; ci < 4; ++ci)
        #pragma unroll
        for (int ri = 0; ri < 4; ++ri)
            At[tc * 4 + ci][tr * 4 + ri] = h[ri][ci];
    __syncthreads();

    #pragma unroll
    for (int i = 0; i < 4; ++i)
        #pragma unroll
        for (int j = 0; j < 4; ++j) acc[i][j] = 0.f;

    #pragma unroll 4
    for (int k = 0; k < DIM; ++k) {
        float4 a = *(const float4*)&At[k][tr * 4];
        float4 w = *(const float4*)&Wl[k * DIM + tc * 4];
        float av[4] = {a.x, a.y, a.z, a.w};
        float wv[4] = {w.x, w.y, w.z, w.w};
        #pragma unroll
        for (int i = 0; i < 4; ++i)
            #pragma unroll
            for (int j = 0; j < 4; ++j)
                acc[i][j] = fmaf(av[i], wv[j], acc[i][j]);
    }

    float4 bv2 = ((const float4*)b2)[tc];
    float4* io4 = (float4*)io;
    #pragma unroll
    for (int ri = 0; ri < 4; ++ri) {
        int row = r0 + tr * 4 + ri;
        if (row < N) {
            float4 o = make_float4(acc[ri][0] + bv2.x, acc[ri][1] + bv2.y,
                                   acc[ri][2] + bv2.z, acc[ri][3] + bv2.w);
            io4[(size_t)row * 32 + tc] = o;
        }
    }
}

extern "C" void kernel_launch(void* const* d_in, const int* in_sizes, int n_in,
                              void* d_out, int out_size, void* d_ws, size_t ws_size,
                              hipStream_t stream) {
    const float* x  = (const float*)d_in[0];
    const int*   ei = (const int*)d_in[1];
    const float* W1 = (const float*)d_in[2];
    const float* b1 = (const float*)d_in[3];
    const float* W2 = (const float*)d_in[4];
    const float* b2 = (const float*)d_in[5];
    float* out = (float*)d_out;

    const size_t need = (size_t)(NNODES + (NNODES + 1) + NEDGES) * sizeof(int);

    if (ws_size >= need) {
        // ws layout: cur/deg[NNODES] | off[NNODES+1] | srclist[NEDGES]
        int* cur = (int*)d_ws;
        int* off = cur + NNODES;
        int* srclist = off + NNODES + 1;

        zero_k<<<(NNODES + 255) / 256, 256, 0, stream>>>(cur, NNODES);
        hist_k<<<(NEDGES + 255) / 256, 256, 0, stream>>>(ei, cur, NEDGES);
        scan_k<<<1, 256, 0, stream>>>(cur, off, NEDGES);
        fill_k<<<(NEDGES + 255) / 256, 256, 0, stream>>>(ei, cur, srclist, NEDGES);

        int gthreads = NNODES * 32;
        gather_k<<<(gthreads + 255) / 256, 256, 0, stream>>>(
            (const float4*)x, off, srclist, (float4*)out);
    } else {
        // fallback: atomic scatter
        int n4 = NNODES * DIM / 4;
        copy_k<<<(n4 + 255) / 256, 256, 0, stream>>>((const float4*)x, (float4*)out, n4);
        int sthreads = NEDGES * 32;
        scatter_k<<<(sthreads + 255) / 256, 256, 0, stream>>>((const float4*)x, ei, out, NEDGES);
    }

    mlp_k<<<(NNODES + 31) / 32, 256, 0, stream>>>(out, W1, b1, W2, b2, NNODES);
}

// Round 3
// 276.574 us; speedup vs baseline: 4.4758x; 1.3799x over previous
//
#include <hip/hip_runtime.h>

#define NNODES 50000
#define NEDGES 640000
#define DIM 128
#define SCAN_BLK 49   // ceil(50000 / 1024)

// ---------------- CSR build ----------------

__global__ void zero_k(int* __restrict__ p, int n) {
    int i = blockIdx.x * blockDim.x + threadIdx.x;
    if (i < n) p[i] = 0;
}

// deg[dst]++ for each edge
__global__ void hist_k(const int* __restrict__ ei, int* __restrict__ deg, int E) {
    int e = blockIdx.x * blockDim.x + threadIdx.x;
    if (e < E) atomicAdd(&deg[ei[E + e]], 1);
}

// phase A: per-block (1024 elems) sums. NNODES % 4 == 0 so int4 loads are clean.
__global__ void scanA_k(const int* __restrict__ deg, int* __restrict__ bsum) {
    const int t = threadIdx.x, b = blockIdx.x;
    const int base = b * 1024 + t * 4;
    int4 v = make_int4(0, 0, 0, 0);
    if (base < NNODES) v = *(const int4*)&deg[base];
    int s = v.x + v.y + v.z + v.w;
    #pragma unroll
    for (int d = 32; d > 0; d >>= 1) s += __shfl_down(s, d, 64);
    __shared__ int ws[4];
    if ((t & 63) == 0) ws[t >> 6] = s;
    __syncthreads();
    if (t == 0) bsum[b] = ws[0] + ws[1] + ws[2] + ws[3];
}

// phase B: one wave scans the block sums (SCAN_BLK <= 64)
__global__ void scanB_k(const int* __restrict__ bsum, int* __restrict__ bbase) {
    const int t = threadIdx.x;  // 64 threads
    int orig = (t < SCAN_BLK) ? bsum[t] : 0;
    int v = orig;
    #pragma unroll
    for (int d = 1; d < 64; d <<= 1) {
        int u = __shfl_up(v, d, 64);
        if (t >= d) v += u;
    }
    if (t < SCAN_BLK) bbase[t] = v - orig;  // exclusive
}

// phase C: per-block exclusive scan + base; write off[] and cur[]
__global__ void scanC_k(const int* __restrict__ deg, const int* __restrict__ bbase,
                        int* __restrict__ off, int* __restrict__ cur) {
    __shared__ int ws[4];
    const int t = threadIdx.x, b = blockIdx.x;
    const int base = b * 1024 + t * 4;
    int4 v = make_int4(0, 0, 0, 0);
    if (base < NNODES) v = *(const int4*)&deg[base];
    const int s = v.x + v.y + v.z + v.w;
    const int lane = t & 63, w = t >> 6;
    int sv = s;
    #pragma unroll
    for (int d = 1; d < 64; d <<= 1) {
        int u = __shfl_up(sv, d, 64);
        if (lane >= d) sv += u;
    }
    if (lane == 63) ws[w] = sv;
    __syncthreads();
    int wbase = 0;
    #pragma unroll
    for (int i = 0; i < 4; ++i) if (i < w) wbase += ws[i];
    int ex = bbase[b] + wbase + (sv - s);  // exclusive prefix for this thread's 4 elems
    if (base < NNODES) {
        int4 o;
        o.x = ex;
        o.y = o.x + v.x;
        o.z = o.y + v.y;
        o.w = o.z + v.z;
        *(int4*)&off[base] = o;
        *(int4*)&cur[base] = o;
    }
    if (b == 0 && t == 0) off[NNODES] = NEDGES;
}

// srclist[cur[dst]++] = src
__global__ void fill_k(const int* __restrict__ ei, int* __restrict__ cur,
                       int* __restrict__ srclist, int E) {
    int e = blockIdx.x * blockDim.x + threadIdx.x;
    if (e >= E) return;
    int src = ei[e];
    int dst = ei[E + e];
    int pos = atomicAdd(&cur[dst], 1);
    srclist[pos] = src;
}

// ---------------- gather aggregation (no atomics) ----------------
__global__ void gather_k(const float4* __restrict__ x4, const int* __restrict__ off,
                         const int* __restrict__ srclist, float4* __restrict__ hp4) {
    int t = blockIdx.x * blockDim.x + threadIdx.x;
    int node = t >> 5;
    if (node >= NNODES) return;
    int lane = t & 31;
    float4 acc = x4[(size_t)node * 32 + lane];
    int beg = off[node], end = off[node + 1];
    for (int j = beg; j < end; ++j) {
        int s = srclist[j];
        float4 v = x4[(size_t)s * 32 + lane];
        acc.x += v.x; acc.y += v.y; acc.z += v.z; acc.w += v.w;
    }
    hp4[(size_t)node * 32 + lane] = acc;
}

// ---------------- fallback atomic scatter (if ws too small) ----------------
__global__ void copy_k(const float4* __restrict__ src, float4* __restrict__ dst, int n4) {
    int i = blockIdx.x * blockDim.x + threadIdx.x;
    if (i < n4) dst[i] = src[i];
}

__global__ void scatter_k(const float4* __restrict__ x4, const int* __restrict__ ei,
                          float* __restrict__ hp, int E) {
    int t = blockIdx.x * blockDim.x + threadIdx.x;
    int e = t >> 5;
    if (e >= E) return;
    int lane = t & 31;
    int src = ei[e];
    int dst = ei[E + e];
    float4 v = x4[(size_t)src * 32 + lane];
    float* p = hp + (size_t)dst * DIM + lane * 4;
    unsafeAtomicAdd(p + 0, v.x);
    unsafeAtomicAdd(p + 1, v.y);
    unsafeAtomicAdd(p + 2, v.z);
    unsafeAtomicAdd(p + 3, v.w);
}

// ---------------- fused MLP ----------------
__launch_bounds__(256)
__global__ void mlp_k(float* __restrict__ io,
                      const float* __restrict__ W1, const float* __restrict__ b1,
                      const float* __restrict__ W2, const float* __restrict__ b2,
                      int N) {
    __shared__ float Wl[DIM * DIM];   // 64 KB
    __shared__ float At[DIM][32];     // 16 KB

    const int tid = threadIdx.x;
    const int r0 = blockIdx.x * 32;
    const int tc = tid & 31;
    const int tr = tid >> 5;

    {
        const float4* w4 = (const float4*)W1;
        float4* wl4 = (float4*)Wl;
        #pragma unroll
        for (int i = 0; i < 16; ++i) wl4[tid + i * 256] = w4[tid + i * 256];
    }
    {
        const float4* io4 = (const float4*)io;
        #pragma unroll
        for (int i = 0; i < 4; ++i) {
            int p = tid + i * 256;
            int row = p >> 5;
            int k4 = p & 31;
            float4 v = make_float4(0.f, 0.f, 0.f, 0.f);
            if (r0 + row < N) v = io4[(size_t)(r0 + row) * 32 + k4];
            At[k4 * 4 + 0][row] = v.x;
            At[k4 * 4 + 1][row] = v.y;
            At[k4 * 4 + 2][row] = v.z;
            At[k4 * 4 + 3][row] = v.w;
        }
    }
    __syncthreads();

    float acc[4][4];
    #pragma unroll
    for (int i = 0; i < 4; ++i)
        #pragma unroll
        for (int j = 0; j < 4; ++j) acc[i][j] = 0.f;

    #pragma unroll 4
    for (int k = 0; k < DIM; ++k) {
        float4 a = *(const float4*)&At[k][tr * 4];
        float4 w = *(const float4*)&Wl[k * DIM + tc * 4];
        float av[4] = {a.x, a.y, a.z, a.w};
        float wv[4] = {w.x, w.y, w.z, w.w};
        #pragma unroll
        for (int i = 0; i < 4; ++i)
            #pragma unroll
            for (int j = 0; j < 4; ++j)
                acc[i][j] = fmaf(av[i], wv[j], acc[i][j]);
    }

    float4 bv1 = ((const float4*)b1)[tc];
    float h[4][4];
    #pragma unroll
    for (int i = 0; i < 4; ++i) {
        h[i][0] = fmaxf(acc[i][0] + bv1.x, 0.f);
        h[i][1] = fmaxf(acc[i][1] + bv1.y, 0.f);
        h[i][2] = fmaxf(acc[i][2] + bv1.z, 0.f);
        h[i][3] = fmaxf(acc[i][3] + bv1.w, 0.f);
    }

    __syncthreads();

    {
        const float4* w4 = (const float4*)W2;
        float4* wl4 = (float4*)Wl;
        #pragma unroll
        for (int i = 0; i < 16; ++i) wl4[tid + i * 256] = w4[tid + i * 256];
    }
    #pragma unroll
    for (int ci = 0; ci < 4; ++ci)
        #pragma unroll
        for (int ri = 0; ri < 4; ++ri)
            At[tc * 4 + ci][tr * 4 + ri] = h[ri][ci];
    __syncthreads();

    #pragma unroll
    for (int i = 0; i < 4; ++i)
        #pragma unroll
        for (int j = 0; j < 4; ++j) acc[i][j] = 0.f;

    #pragma unroll 4
    for (int k = 0; k < DIM; ++k) {
        float4 a = *(const float4*)&At[k][tr * 4];
        float4 w = *(const float4*)&Wl[k * DIM + tc * 4];
        float av[4] = {a.x, a.y, a.z, a.w};
        float wv[4] = {w.x, w.y, w.z, w.w};
        #pragma unroll
        for (int i = 0; i < 4; ++i)
            #pragma unroll
            for (int j = 0; j < 4; ++j)
                acc[i][j] = fmaf(av[i], wv[j], acc[i][j]);
    }

    float4 bv2 = ((const float4*)b2)[tc];
    float4* io4 = (float4*)io;
    #pragma unroll
    for (int ri = 0; ri < 4; ++ri) {
        int row = r0 + tr * 4 + ri;
        if (row < N) {
            float4 o = make_float4(acc[ri][0] + bv2.x, acc[ri][1] + bv2.y,
                                   acc[ri][2] + bv2.z, acc[ri][3] + bv2.w);
            io4[(size_t)row * 32 + tc] = o;
        }
    }
}

extern "C" void kernel_launch(void* const* d_in, const int* in_sizes, int n_in,
                              void* d_out, int out_size, void* d_ws, size_t ws_size,
                              hipStream_t stream) {
    const float* x  = (const float*)d_in[0];
    const int*   ei = (const int*)d_in[1];
    const float* W1 = (const float*)d_in[2];
    const float* b1 = (const float*)d_in[3];
    const float* W2 = (const float*)d_in[4];
    const float* b2 = (const float*)d_in[5];
    float* out = (float*)d_out;

    // ws layout: deg[NNODES] | cur[NNODES] | off[NNODES+1] | srclist[NEDGES] | bsum[64] | bbase[64]
    const size_t need = (size_t)(NNODES * 2 + (NNODES + 1) + NEDGES + 128) * sizeof(int);

    if (ws_size >= need) {
        int* deg = (int*)d_ws;
        int* cur = deg + NNODES;
        int* off = cur + NNODES;
        int* srclist = off + NNODES + 1;
        int* bsum = srclist + NEDGES;
        int* bbase = bsum + 64;

        zero_k<<<(NNODES + 255) / 256, 256, 0, stream>>>(deg, NNODES);
        hist_k<<<(NEDGES + 255) / 256, 256, 0, stream>>>(ei, deg, NEDGES);
        scanA_k<<<SCAN_BLK, 256, 0, stream>>>(deg, bsum);
        scanB_k<<<1, 64, 0, stream>>>(bsum, bbase);
        scanC_k<<<SCAN_BLK, 256, 0, stream>>>(deg, bbase, off, cur);
        fill_k<<<(NEDGES + 255) / 256, 256, 0, stream>>>(ei, cur, srclist, NEDGES);

        int gthreads = NNODES * 32;
        gather_k<<<(gthreads + 255) / 256, 256, 0, stream>>>(
            (const float4*)x, off, srclist, (float4*)out);
    } else {
        int n4 = NNODES * DIM / 4;
        copy_k<<<(n4 + 255) / 256, 256, 0, stream>>>((const float4*)x, (float4*)out, n4);
        int sthreads = NEDGES * 32;
        scatter_k<<<(sthreads + 255) / 256, 256, 0, stream>>>((const float4*)x, ei, out, NEDGES);
    }

    mlp_k<<<(NNODES + 31) / 32, 256, 0, stream>>>(out, W1, b1, W2, b2, NNODES);
}

// Round 5
// 261.292 us; speedup vs baseline: 4.7376x; 1.0585x over previous
//
#include <hip/hip_runtime.h>

#define NNODES 50000
#define NEDGES 640000
#define DIM 128
#define SCAN_BLK 49   // ceil(50000 / 1024)

// ---------------- CSR build ----------------

__global__ void zero_k(int* __restrict__ p, int n) {
    int i = blockIdx.x * blockDim.x + threadIdx.x;
    if (i < n) p[i] = 0;
}

// deg[dst]++ for each edge
__global__ void hist_k(const int* __restrict__ ei, int* __restrict__ deg, int E) {
    int e = blockIdx.x * blockDim.x + threadIdx.x;
    if (e < E) atomicAdd(&deg[ei[E + e]], 1);
}

// phase A: per-block (1024 elems) sums
__global__ void scanA_k(const int* __restrict__ deg, int* __restrict__ bsum) {
    const int t = threadIdx.x, b = blockIdx.x;
    const int base = b * 1024 + t * 4;
    int4 v = make_int4(0, 0, 0, 0);
    if (base < NNODES) v = *(const int4*)&deg[base];
    int s = v.x + v.y + v.z + v.w;
    #pragma unroll
    for (int d = 32; d > 0; d >>= 1) s += __shfl_down(s, d, 64);
    __shared__ int ws[4];
    if ((t & 63) == 0) ws[t >> 6] = s;
    __syncthreads();
    if (t == 0) bsum[b] = ws[0] + ws[1] + ws[2] + ws[3];
}

// phase B: one wave scans the block sums (SCAN_BLK <= 64)
__global__ void scanB_k(const int* __restrict__ bsum, int* __restrict__ bbase) {
    const int t = threadIdx.x;
    int orig = (t < SCAN_BLK) ? bsum[t] : 0;
    int v = orig;
    #pragma unroll
    for (int d = 1; d < 64; d <<= 1) {
        int u = __shfl_up(v, d, 64);
        if (t >= d) v += u;
    }
    if (t < SCAN_BLK) bbase[t] = v - orig;
}

// phase C: per-block exclusive scan + base; write off[] and cur[]
__global__ void scanC_k(const int* __restrict__ deg, const int* __restrict__ bbase,
                        int* __restrict__ off, int* __restrict__ cur) {
    __shared__ int ws[4];
    const int t = threadIdx.x, b = blockIdx.x;
    const int base = b * 1024 + t * 4;
    int4 v = make_int4(0, 0, 0, 0);
    if (base < NNODES) v = *(const int4*)&deg[base];
    const int s = v.x + v.y + v.z + v.w;
    const int lane = t & 63, w = t >> 6;
    int sv = s;
    #pragma unroll
    for (int d = 1; d < 64; d <<= 1) {
        int u = __shfl_up(sv, d, 64);
        if (lane >= d) sv += u;
    }
    if (lane == 63) ws[w] = sv;
    __syncthreads();
    int wbase = 0;
    #pragma unroll
    for (int i = 0; i < 4; ++i) if (i < w) wbase += ws[i];
    int ex = bbase[b] + wbase + (sv - s);
    if (base < NNODES) {
        int4 o;
        o.x = ex;
        o.y = o.x + v.x;
        o.z = o.y + v.y;
        o.w = o.z + v.z;
        *(int4*)&off[base] = o;
        *(int4*)&cur[base] = o;
    }
    if (b == 0 && t == 0) off[NNODES] = NEDGES;
}

// srclist[cur[dst]++] = src
__global__ void fill_k(const int* __restrict__ ei, int* __restrict__ cur,
                       int* __restrict__ srclist, int E) {
    int e = blockIdx.x * blockDim.x + threadIdx.x;
    if (e >= E) return;
    int src = ei[e];
    int dst = ei[E + e];
    int pos = atomicAdd(&cur[dst], 1);
    srclist[pos] = src;
}

// ---------------- gather aggregation (no atomics) ----------------
__global__ void gather_k(const float4* __restrict__ x4, const int* __restrict__ off,
                         const int* __restrict__ srclist, float4* __restrict__ hp4) {
    int t = blockIdx.x * blockDim.x + threadIdx.x;
    int node = t >> 5;
    if (node >= NNODES) return;
    int lane = t & 31;
    float4 acc = x4[(size_t)node * 32 + lane];
    int beg = off[node], end = off[node + 1];
    for (int j = beg; j < end; ++j) {
        int s = srclist[j];
        float4 v = x4[(size_t)s * 32 + lane];
        acc.x += v.x; acc.y += v.y; acc.z += v.z; acc.w += v.w;
    }
    hp4[(size_t)node * 32 + lane] = acc;
}

// ---------------- fallback atomic scatter (if ws too small) ----------------
__global__ void copy_k(const float4* __restrict__ src, float4* __restrict__ dst, int n4) {
    int i = blockIdx.x * blockDim.x + threadIdx.x;
    if (i < n4) dst[i] = src[i];
}

__global__ void scatter_k(const float4* __restrict__ x4, const int* __restrict__ ei,
                          float* __restrict__ hp, int E) {
    int t = blockIdx.x * blockDim.x + threadIdx.x;
    int e = t >> 5;
    if (e >= E) return;
    int lane = t & 31;
    int src = ei[e];
    int dst = ei[E + e];
    float4 v = x4[(size_t)src * 32 + lane];
    float* p = hp + (size_t)dst * DIM + lane * 4;
    unsafeAtomicAdd(p + 0, v.x);
    unsafeAtomicAdd(p + 1, v.y);
    unsafeAtomicAdd(p + 2, v.z);
    unsafeAtomicAdd(p + 3, v.w);
}

// ---------------- fused MLP — conflict-free LDS layout ----------------
// A stays ROW-major in LDS. All LDS traffic is either lane-contiguous b128
// (staging, h write-back) or half-wave broadcast (A reads) -> no transposes,
// no bank conflicts, no padding needed.
__launch_bounds__(256)
__global__ void mlp_k(float* __restrict__ io,
                      const float* __restrict__ W1, const float* __restrict__ b1,
                      const float* __restrict__ W2, const float* __restrict__ b2,
                      int N) {
    __shared__ float Wl[DIM * DIM];   // 64 KB, W[k][c] row-major
    __shared__ float As[32][DIM];     // 16 KB, A[r][k] row-major

    const int tid = threadIdx.x;
    const int r0 = blockIdx.x * 32;
    const int tc = tid & 31;
    const int tr = tid >> 5;   // 0..7 -> rows tr*4..tr*4+3, cols tc*4..tc*4+3

    // stage W1 (contiguous float4 -> conflict-free)
    {
        const float4* w4 = (const float4*)W1;
        float4* wl4 = (float4*)Wl;
        #pragma unroll
        for (int i = 0; i < 16; ++i) wl4[tid + i * 256] = w4[tid + i * 256];
    }
    // stage A row-major (straight contiguous copy -> conflict-free)
    {
        const float4* io4 = (const float4*)io;
        float4* as4 = (float4*)As;
        #pragma unroll
        for (int i = 0; i < 4; ++i) {
            int p = tid + i * 256;           // [0,1024): row=p>>5, k4=p&31
            int row = p >> 5;
            float4 v = make_float4(0.f, 0.f, 0.f, 0.f);
            if (r0 + row < N) v = io4[(size_t)(r0 + row) * 32 + (p & 31)];
            as4[p] = v;
        }
    }
    __syncthreads();

    // ---- layer 1 ----
    float acc[4][4];
    #pragma unroll
    for (int i = 0; i < 4; ++i)
        #pragma unroll
        for (int j = 0; j < 4; ++j) acc[i][j] = 0.f;

    for (int kc = 0; kc < 32; ++kc) {      // 4 k's per iteration
        float4 a[4], w[4];
        #pragma unroll
        for (int i = 0; i < 4; ++i) a[i] = *(const float4*)&As[tr * 4 + i][kc * 4];
        #pragma unroll
        for (int kk = 0; kk < 4; ++kk) w[kk] = *(const float4*)&Wl[(kc * 4 + kk) * DIM + tc * 4];
        float af[4][4];
        #pragma unroll
        for (int i = 0; i < 4; ++i) {
            af[i][0] = a[i].x; af[i][1] = a[i].y; af[i][2] = a[i].z; af[i][3] = a[i].w;
        }
        #pragma unroll
        for (int kk = 0; kk < 4; ++kk) {
            float wv[4] = {w[kk].x, w[kk].y, w[kk].z, w[kk].w};
            #pragma unroll
            for (int i = 0; i < 4; ++i)
                #pragma unroll
                for (int j = 0; j < 4; ++j)
                    acc[i][j] = fmaf(af[i][kk], wv[j], acc[i][j]);
        }
    }

    float4 bv1 = ((const float4*)b1)[tc];
    float h[4][4];
    #pragma unroll
    for (int i = 0; i < 4; ++i) {
        h[i][0] = fmaxf(acc[i][0] + bv1.x, 0.f);
        h[i][1] = fmaxf(acc[i][1] + bv1.y, 0.f);
        h[i][2] = fmaxf(acc[i][2] + bv1.z, 0.f);
        h[i][3] = fmaxf(acc[i][3] + bv1.w, 0.f);
    }

    __syncthreads();  // everyone done reading W1/As

    // stage W2; write h back row-major (lane-contiguous b128 -> conflict-free)
    {
        const float4* w4 = (const float4*)W2;
        float4* wl4 = (float4*)Wl;
        #pragma unroll
        for (int i = 0; i < 16; ++i) wl4[tid + i * 256] = w4[tid + i * 256];
    }
    #pragma unroll
    for (int i = 0; i < 4; ++i)
        *(float4*)&As[tr * 4 + i][tc * 4] = make_float4(h[i][0], h[i][1], h[i][2], h[i][3]);
    __syncthreads();

    // ---- layer 2 ----
    #pragma unroll
    for (int i = 0; i < 4; ++i)
        #pragma unroll
        for (int j = 0; j < 4; ++j) acc[i][j] = 0.f;

    for (int kc = 0; kc < 32; ++kc) {
        float4 a[4], w[4];
        #pragma unroll
        for (int i = 0; i < 4; ++i) a[i] = *(const float4*)&As[tr * 4 + i][kc * 4];
        #pragma unroll
        for (int kk = 0; kk < 4; ++kk) w[kk] = *(const float4*)&Wl[(kc * 4 + kk) * DIM + tc * 4];
        float af[4][4];
        #pragma unroll
        for (int i = 0; i < 4; ++i) {
            af[i][0] = a[i].x; af[i][1] = a[i].y; af[i][2] = a[i].z; af[i][3] = a[i].w;
        }
        #pragma unroll
        for (int kk = 0; kk < 4; ++kk) {
            float wv[4] = {w[kk].x, w[kk].y, w[kk].z, w[kk].w};
            #pragma unroll
            for (int i = 0; i < 4; ++i)
                #pragma unroll
                for (int j = 0; j < 4; ++j)
                    acc[i][j] = fmaf(af[i][kk], wv[j], acc[i][j]);
        }
    }

    float4 bv2 = ((const float4*)b2)[tc];
    float4* io4 = (float4*)io;
    #pragma unroll
    for (int ri = 0; ri < 4; ++ri) {
        int row = r0 + tr * 4 + ri;
        if (row < N) {
            float4 o = make_float4(acc[ri][0] + bv2.x, acc[ri][1] + bv2.y,
                                   acc[ri][2] + bv2.z, acc[ri][3] + bv2.w);
            io4[(size_t)row * 32 + tc] = o;
        }
    }
}

extern "C" void kernel_launch(void* const* d_in, const int* in_sizes, int n_in,
                              void* d_out, int out_size, void* d_ws, size_t ws_size,
                              hipStream_t stream) {
    const float* x  = (const float*)d_in[0];
    const int*   ei = (const int*)d_in[1];
    const float* W1 = (const float*)d_in[2];
    const float* b1 = (const float*)d_in[3];
    const float* W2 = (const float*)d_in[4];
    const float* b2 = (const float*)d_in[5];
    float* out = (float*)d_out;

    // ws layout: deg[NNODES] | cur[NNODES] | off[NNODES+1] | srclist[NEDGES] | bsum[64] | bbase[64]
    const size_t need = (size_t)(NNODES * 2 + (NNODES + 1) + NEDGES + 128) * sizeof(int);

    if (ws_size >= need) {
        int* deg = (int*)d_ws;
        int* cur = deg + NNODES;
        int* off = cur + NNODES;
        int* srclist = off + NNODES + 1;
        int* bsum = srclist + NEDGES;
        int* bbase = bsum + 64;

        zero_k<<<(NNODES + 255) / 256, 256, 0, stream>>>(deg, NNODES);
        hist_k<<<(NEDGES + 255) / 256, 256, 0, stream>>>(ei, deg, NEDGES);
        scanA_k<<<SCAN_BLK, 256, 0, stream>>>(deg, bsum);
        scanB_k<<<1, 64, 0, stream>>>(bsum, bbase);
        scanC_k<<<SCAN_BLK, 256, 0, stream>>>(deg, bbase, off, cur);
        fill_k<<<(NEDGES + 255) / 256, 256, 0, stream>>>(ei, cur, srclist, NEDGES);

        int gthreads = NNODES * 32;
        gather_k<<<(gthreads + 255) / 256, 256, 0, stream>>>(
            (const float4*)x, off, srclist, (float4*)out);
    } else {
        int n4 = NNODES * DIM / 4;
        copy_k<<<(n4 + 255) / 256, 256, 0, stream>>>((const float4*)x, (float4*)out, n4);
        int sthreads = NEDGES * 32;
        scatter_k<<<(sthreads + 255) / 256, 256, 0, stream>>>((const float4*)x, ei, out, NEDGES);
    }

    mlp_k<<<(NNODES + 31) / 32, 256, 0, stream>>>(out, W1, b1, W2, b2, NNODES);
}